// Round 11
// baseline (141.707 us; speedup 1.0000x reference)
//
#include <hip/hip_runtime.h>

// Output = jacobi(X, Mask1, 100) — the multigrid sweeps in the reference are
// dead code for the returned value (grids[0] is never mutated).
//
// Trapezoidal temporal blocking, register-resident: 5 launches x 20 fused
// iterations (halves launch overhead + prologue count vs 10x10).
// Tile 128x128, 512 threads, 8-tall x 4-wide cells/thread (halo exchange
// 6 B/cell). Grid 12x12 = 144 blocks <= 256 CUs -> 1 block/CU critical path.
// LDS = double-buffered edge strips {T,B,L0,L1,R0,R1} (114.8 KB),
// 1 barrier/iter, final iter skips publish+barrier. Guard-ring-only zero
// merged with initial publish under a single barrier.
// Tile edges compute bounded garbage that never reaches the valid 88x88
// window (light-cone: garbage advances 1 cell/iter, valid cells are >= TI
// from the edge); the zeroed ring doubles as zero padding at domain edges
// (mask=0 outside keeps exterior cells at 0).

#define W 1024
#define H 1024
#define TILE 128
#define TI 20                    // fused iterations per launch
#define OS 88                    // valid rows/cols per tile: [20, 108)
#define NB 12                    // 12*88 = 1056 >= 1024
#define NLAUNCH 5                // NLAUNCH * TI = 100

// strip grids: 16 patch-rows x 32 patch-cols + guard ring
#define SRr 18
#define SRc 34
#define S_T  0
#define S_B  1
#define S_L0 2
#define S_L1 3
#define S_R0 4
#define S_R1 5

__device__ __forceinline__ float4 ld4(const float* __restrict__ p, int gr, int gc) {
    // gc is a multiple of 4 and W%4==0 -> the quad is entirely in or out
    if ((unsigned)gr < (unsigned)H && (unsigned)gc < (unsigned)W)
        return *(const float4*)&p[gr * W + gc];
    return make_float4(0.f, 0.f, 0.f, 0.f);
}

__device__ __forceinline__ float4 rowstep(const float4 up, const float4 ce,
                                          const float4 dn, const float lf,
                                          const float rt, const float4 m) {
    float4 s, n;
    s.x = (up.x + dn.x) + (lf   + ce.y);
    s.y = (up.y + dn.y) + (ce.x + ce.z);
    s.z = (up.z + dn.z) + (ce.y + ce.w);
    s.w = (up.w + dn.w) + (ce.z + rt);
    n.x = fmaf(m.x, fmaf(0.25f, s.x, -ce.x), ce.x);
    n.y = fmaf(m.y, fmaf(0.25f, s.y, -ce.y), ce.y);
    n.z = fmaf(m.z, fmaf(0.25f, s.z, -ce.z), ce.z);
    n.w = fmaf(m.w, fmaf(0.25f, s.w, -ce.w), ce.w);
    return n;
}

__global__ __launch_bounds__(512, 1) void jacobi_trap(
    const float* __restrict__ xin, const float* __restrict__ mask,
    float* __restrict__ xout)
{
    __shared__ float4 S[2][6][SRr][SRc];   // 114.75 KB

    const int tid = threadIdx.x;
    const int pr = tid >> 5;               // 0..15 (8 rows each)
    const int pc = tid & 31;               // 0..31 (4 cols each)
    const int gx0 = (int)blockIdx.x * OS - TI;
    const int gy0 = (int)blockIdx.y * OS - TI;
    const int gr0 = gy0 + pr * 8;
    const int gc0 = gx0 + pc * 4;          // multiple of 4

    // zero ONLY the guard rings of both buffers' 6 strips (1200 float4s);
    // interiors are fully overwritten by publishes before any read.
    #pragma unroll
    for (int k = 0; k < 3; ++k) {
        int idx = tid + k * 512;
        if (idx < 1200) {
            int bs  = idx / 100;           // 0..11 = buf*6 + strip
            int pos = idx - bs * 100;      // 0..99 around the ring
            float4* st = &S[bs / 6][bs % 6][0][0];
            int r, cc;
            if      (pos < 34) { r = 0;            cc = pos;      }
            else if (pos < 68) { r = SRr - 1;      cc = pos - 34; }
            else if (pos < 84) { r = pos - 68 + 1; cc = 0;        }
            else               { r = pos - 84 + 1; cc = SRc - 1;  }
            st[r * SRc + cc] = make_float4(0.f, 0.f, 0.f, 0.f);
        }
    }

    // cells + mask -> registers (mask reused for all TI iterations)
    float4 c[8], m[8];
    #pragma unroll
    for (int i = 0; i < 8; ++i) {
        c[i] = ld4(xin,  gr0 + i, gc0);
        m[i] = ld4(mask, gr0 + i, gc0);
    }

    // publish initial edges into buffer 0 interior (disjoint from ring)
    S[0][S_T ][pr + 1][pc + 1] = c[0];
    S[0][S_B ][pr + 1][pc + 1] = c[7];
    S[0][S_L0][pr + 1][pc + 1] = make_float4(c[0].x, c[1].x, c[2].x, c[3].x);
    S[0][S_L1][pr + 1][pc + 1] = make_float4(c[4].x, c[5].x, c[6].x, c[7].x);
    S[0][S_R0][pr + 1][pc + 1] = make_float4(c[0].w, c[1].w, c[2].w, c[3].w);
    S[0][S_R1][pr + 1][pc + 1] = make_float4(c[4].w, c[5].w, c[6].w, c[7].w);
    __syncthreads();

    #pragma unroll 1
    for (int it = 0; it < TI; ++it) {
        const int rb = it & 1;
        const float4 th  = S[rb][S_B ][pr    ][pc + 1];  // above's bottom row
        const float4 bh  = S[rb][S_T ][pr + 2][pc + 1];  // below's top row
        const float4 lh0 = S[rb][S_R0][pr + 1][pc    ];  // left's right col 0-3
        const float4 lh1 = S[rb][S_R1][pr + 1][pc    ];  // left's right col 4-7
        const float4 rh0 = S[rb][S_L0][pr + 1][pc + 2];  // right's left col 0-3
        const float4 rh1 = S[rb][S_L1][pr + 1][pc + 2];  // right's left col 4-7

        float4 n[8];
        n[0] = rowstep(th,   c[0], c[1], lh0.x, rh0.x, m[0]);
        n[1] = rowstep(c[0], c[1], c[2], lh0.y, rh0.y, m[1]);
        n[2] = rowstep(c[1], c[2], c[3], lh0.z, rh0.z, m[2]);
        n[3] = rowstep(c[2], c[3], c[4], lh0.w, rh0.w, m[3]);
        n[4] = rowstep(c[3], c[4], c[5], lh1.x, rh1.x, m[4]);
        n[5] = rowstep(c[4], c[5], c[6], lh1.y, rh1.y, m[5]);
        n[6] = rowstep(c[5], c[6], c[7], lh1.z, rh1.z, m[6]);
        n[7] = rowstep(c[6], c[7], bh,   lh1.w, rh1.w, m[7]);
        #pragma unroll
        for (int i = 0; i < 8; ++i) c[i] = n[i];

        if (it < TI - 1) {   // last iter: nobody reads these edges
            const int wb = rb ^ 1;
            S[wb][S_T ][pr + 1][pc + 1] = n[0];
            S[wb][S_B ][pr + 1][pc + 1] = n[7];
            S[wb][S_L0][pr + 1][pc + 1] = make_float4(n[0].x, n[1].x, n[2].x, n[3].x);
            S[wb][S_L1][pr + 1][pc + 1] = make_float4(n[4].x, n[5].x, n[6].x, n[7].x);
            S[wb][S_R0][pr + 1][pc + 1] = make_float4(n[0].w, n[1].w, n[2].w, n[3].w);
            S[wb][S_R1][pr + 1][pc + 1] = make_float4(n[4].w, n[5].w, n[6].w, n[7].w);
            __syncthreads();
        }
    }

    // store valid window: rows/cols [TI, TILE-TI) = [20, 108)
    if (pc >= 5 && pc <= 26 && (unsigned)gc0 < (unsigned)W) {
        #pragma unroll
        for (int i = 0; i < 8; ++i) {
            int lr = pr * 8 + i;
            if (lr < TI || lr >= TILE - TI) continue;
            int gr = gy0 + lr;
            if ((unsigned)gr >= (unsigned)H) continue;
            *(float4*)&xout[gr * W + gc0] = c[i];
        }
    }
}

extern "C" void kernel_launch(void* const* d_in, const int* in_sizes, int n_in,
                              void* d_out, int out_size, void* d_ws, size_t ws_size,
                              hipStream_t stream) {
    const float* X = (const float*)d_in[0];   // (1,1,1024,1024)
    const float* M = (const float*)d_in[1];   // Mask1
    float* out = (float*)d_out;
    float* ws  = (float*)d_ws;                // 4 MB ping buffer

    dim3 grid(NB, NB), block(512);
    // l=0: X->ws; l odd -> out; l=4 (even)... NLAUNCH=5: l = 0,1,2,3,4
    // writes ws,out,ws,out,ws — final must be d_out, so flip parity:
    // dst = (l & 1) ? ws : out for l>=1? Simpler: choose so l==NLAUNCH-1 -> out.
    const float* src = X;
    for (int l = 0; l < NLAUNCH; ++l) {
        // last launch writes out; alternate backwards from there
        float* dst = ((NLAUNCH - 1 - l) & 1) ? ws : out;
        jacobi_trap<<<grid, block, 0, stream>>>(src, M, dst);
        src = dst;
    }
}

// Round 14
// 102.804 us; speedup vs baseline: 1.3784x; 1.3784x over previous
//
#include <hip/hip_runtime.h>

// Output = jacobi(X, Mask1, 100) — the multigrid sweeps in the reference are
// dead code for the returned value (grids[0] is never mutated).
//
// Trapezoidal temporal blocking, register-resident (r10 geometry: 10 launches
// x TI=10, 128x64 tile, 512 threads, 4x4 cells/thread, 240 blocks = 1/CU).
//
// Intra-wave vertical halo exchange via permlane32_swap made INTERPRETATION-
// PROOF (r12 asm and r13 builtin both failed identically -> the data-movement
// convention, not hazards, was wrong): each thread publishes the one row its
// partner needs, p = lowHalf ? c[3] : c[0], and partner_p is recovered as
// r.x ^ r.y ^ p where r = permlane32_swap(p, p). Per lane, one return slot
// holds own p and the other holds partner p under EVERY combination of swap
// direction and return order, so the XOR identity is unconditionally exact
// (bitwise). T/B LDS strips carry only cross-wave boundaries (half-exec),
// cutting DS work/iter ~25% vs r10; the exchange rides the VALU pipe.
//
// Guard-ring-only zeroing merged with initial publish (one prologue barrier).
// Tile edges compute bounded garbage that never reaches the valid window
// (light-cone: HX=12 > TI-1, TI rows); exterior cells stay 0 via mask=0.

#define W 1024
#define H 1024
#define TILE_W 128
#define TILE_H 64
#define TI 10                    // fused iterations per launch
#define OS_X 104                 // valid cols per tile: [12, 116)
#define OS_Y 44                  // valid rows per tile: [10, 54)
#define HX 12                    // left col halo (>= TI, keeps 16B alignment)
#define NBX 10                   // 10*104 = 1040 >= 1024
#define NBY 24                   // 24*44  = 1056 >= 1024
#define NLAUNCH 10               // NLAUNCH * TI = 100

typedef unsigned uint2v __attribute__((ext_vector_type(2)));

__device__ __forceinline__ float4 ld4(const float* __restrict__ p, int gr, int gc) {
    // gc is a multiple of 4 and W%4==0 -> the quad is entirely in or out
    if ((unsigned)gr < (unsigned)H && (unsigned)gc < (unsigned)W)
        return *(const float4*)&p[gr * W + gc];
    return make_float4(0.f, 0.f, 0.f, 0.f);
}

__device__ __forceinline__ float4 rowstep(const float4 up, const float4 ce,
                                          const float4 dn, const float lf,
                                          const float rt, const float4 m) {
    float4 s, n;
    s.x = (up.x + dn.x) + (lf   + ce.y);
    s.y = (up.y + dn.y) + (ce.x + ce.z);
    s.z = (up.z + dn.z) + (ce.y + ce.w);
    s.w = (up.w + dn.w) + (ce.z + rt);
    n.x = fmaf(m.x, fmaf(0.25f, s.x, -ce.x), ce.x);
    n.y = fmaf(m.y, fmaf(0.25f, s.y, -ce.y), ce.y);
    n.z = fmaf(m.z, fmaf(0.25f, s.z, -ce.z), ce.z);
    n.w = fmaf(m.w, fmaf(0.25f, s.w, -ce.w), ce.w);
    return n;
}

// lane l <-> lane l^32 exchange of p, robust to permlane32_swap convention:
// r holds {own p, partner p} in SOME order per lane -> XOR recovers partner.
__device__ __forceinline__ float xchg32(float p) {
    unsigned u = __float_as_uint(p);
    uint2v r = __builtin_amdgcn_permlane32_swap(u, u, false, false);
    return __uint_as_float(r.x ^ r.y ^ u);
}

__device__ __forceinline__ float4 xchg32_4(const float4 p) {
    return make_float4(xchg32(p.x), xchg32(p.y), xchg32(p.z), xchg32(p.w));
}

__device__ __forceinline__ float4 sel4(bool c, const float4 a, const float4 b) {
    return make_float4(c ? a.x : b.x, c ? a.y : b.y,
                       c ? a.z : b.z, c ? a.w : b.w);
}

__global__ __launch_bounds__(512, 1) void jacobi_trap(
    const float* __restrict__ xin, const float* __restrict__ mask,
    float* __restrict__ xout)
{
    __shared__ float4 SLs[2][18][34];   // left-col packs  (+ col guards)
    __shared__ float4 SRs[2][18][34];   // right-col packs
    __shared__ float4 STs[2][10][32];   // wave top rows   (+ row guards)
    __shared__ float4 SBs[2][10][32];   // wave bottom rows

    const int tid = threadIdx.x;
    const int pr  = tid >> 5;              // 0..15
    const int pc  = tid & 31;              // 0..31
    const int wid = tid >> 6;              // wave 0..7
    const bool lowHalf = (tid & 32) == 0;  // lanes<32 = upper patch (pr even)
    const int gx0 = (int)blockIdx.x * OS_X - HX;
    const int gy0 = (int)blockIdx.y * OS_Y - TI;
    const int gr0 = gy0 + pr * 4;
    const int gc0 = gx0 + pc * 4;          // multiple of 4

    // cells + mask -> registers first (global loads in flight early)
    float4 c[4], m[4];
    #pragma unroll
    for (int i = 0; i < 4; ++i) {
        c[i] = ld4(xin,  gr0 + i, gc0);
        m[i] = ld4(mask, gr0 + i, gc0);
    }

    // zero ONLY the read guard ring (deterministic, NaN-free halos):
    // SRs col 0, SLs col 33 (rows 0..17, both bufs); STs row 9, SBs row 0.
    const float4 z4 = make_float4(0.f, 0.f, 0.f, 0.f);
    if (tid < 72) {
        int b = tid / 36, r2 = tid % 36;
        if (r2 < 18) SRs[b][r2][0] = z4;
        else         SLs[b][r2 - 18][33] = z4;
    } else if (tid >= 128 && tid < 256) {
        int j = tid - 128, b = j >> 6, r3 = j & 63;
        if (r3 < 32) STs[b][9][r3] = z4;
        else         SBs[b][0][r3 - 32] = z4;
    }

    // publish initial edges into buffer 0 (disjoint from guard ring)
    SLs[0][pr + 1][pc + 1] = make_float4(c[0].x, c[1].x, c[2].x, c[3].x);
    SRs[0][pr + 1][pc + 1] = make_float4(c[0].w, c[1].w, c[2].w, c[3].w);
    if (lowHalf) STs[0][wid + 1][pc] = c[0];
    else         SBs[0][wid + 1][pc] = c[3];
    __syncthreads();

    #pragma unroll 1
    for (int it = 0; it < TI; ++it) {
        const int rb = it & 1;

        // intra-wave vertical exchange (VALU pipe, interpretation-proof):
        // I publish the row my partner needs; partner's publish comes back.
        const float4 p4 = sel4(lowHalf, c[3], c[0]);
        const float4 q4 = xchg32_4(p4);   // partner's published row

        // cross-wave vertical via half-exec strips
        float4 thL = z4, bhL = z4;
        if (lowHalf) thL = SBs[rb][wid][pc];          // wave above's bottom
        else         bhL = STs[rb][wid + 2][pc];      // wave below's top
        const float4 th = sel4(lowHalf, thL, q4);     // high: partner's c[3]
        const float4 bh = sel4(lowHalf, q4, bhL);     // low:  partner's c[0]

        const float4 lh = SRs[rb][pr + 1][pc];        // left's right col
        const float4 rh = SLs[rb][pr + 1][pc + 2];    // right's left col

        const float4 n0 = rowstep(th,   c[0], c[1], lh.x, rh.x, m[0]);
        const float4 n1 = rowstep(c[0], c[1], c[2], lh.y, rh.y, m[1]);
        const float4 n2 = rowstep(c[1], c[2], c[3], lh.z, rh.z, m[2]);
        const float4 n3 = rowstep(c[2], c[3], bh,   lh.w, rh.w, m[3]);
        c[0] = n0; c[1] = n1; c[2] = n2; c[3] = n3;

        if (it < TI - 1) {   // last iter: nobody reads these edges
            const int wb = rb ^ 1;
            SLs[wb][pr + 1][pc + 1] = make_float4(n0.x, n1.x, n2.x, n3.x);
            SRs[wb][pr + 1][pc + 1] = make_float4(n0.w, n1.w, n2.w, n3.w);
            if (lowHalf) STs[wb][wid + 1][pc] = n0;
            else         SBs[wb][wid + 1][pc] = n3;
            __syncthreads();
        }
    }

    // store valid window: rows [TI, TILE_H-TI), cols [HX, HX+OS_X)
    const int lc = pc * 4;
    if (lc >= HX && lc < HX + OS_X && (unsigned)gc0 < (unsigned)W) {
        #pragma unroll
        for (int i = 0; i < 4; ++i) {
            int lr = pr * 4 + i;
            if (lr < TI || lr >= TILE_H - TI) continue;
            int gr = gy0 + lr;
            if ((unsigned)gr >= (unsigned)H) continue;
            *(float4*)&xout[gr * W + gc0] = c[i];
        }
    }
}

extern "C" void kernel_launch(void* const* d_in, const int* in_sizes, int n_in,
                              void* d_out, int out_size, void* d_ws, size_t ws_size,
                              hipStream_t stream) {
    const float* X = (const float*)d_in[0];   // (1,1,1024,1024)
    const float* M = (const float*)d_in[1];   // Mask1
    float* out = (float*)d_out;
    float* ws  = (float*)d_ws;                // 4 MB ping buffer

    dim3 grid(NBX, NBY), block(512);
    // l=0: X->ws; alternate; l=9 (odd) -> out. Valid-window union covers
    // the full domain, so ws/out are fully written before any read.
    const float* src = X;
    for (int l = 0; l < NLAUNCH; ++l) {
        float* dst = (l & 1) ? out : ws;
        jacobi_trap<<<grid, block, 0, stream>>>(src, M, dst);
        src = dst;
    }
}